// Round 9
// baseline (366.469 us; speedup 1.0000x reference)
//
#include <hip/hip_runtime.h>
#include <hip/hip_bf16.h>

typedef unsigned short u16;
typedef unsigned int   u32;
typedef __attribute__((ext_vector_type(8))) short bf16x8;   // 8 bf16 = 4 VGPR
typedef __attribute__((ext_vector_type(4))) float f32x4;    // MFMA accum

#define B_  16
#define N_  5000
#define F_  512
#define C_  64
#define FC_ 128
#define NT  (B_ * N_)   // 80000 total nodes

__device__ __forceinline__ float bf2f(u16 h) {
    return __uint_as_float(((u32)h) << 16);
}
__device__ __forceinline__ u16 f2bf(float f) {
    union { __hip_bfloat16 h; u16 s; } c; c.h = __float2bfloat16(f); return c.s;
}
// dtype-flexible scalar weight load (fF: 1 = bf16 data, 0 = fp32 data)
__device__ __forceinline__ float ldw(const void* p, int i, int fF) {
    return fF ? bf2f(((const u16*)p)[i]) : ((const float*)p)[i];
}

// ---------------------------------------------------------------------------
// Detector: flags[0] = 1 if float tensors are bf16 (else fp32)
//           flags[1] = 1 if edge_index is int64 (else int32)
// NOTE (r7): harness inputs are fp32 (in_npz 153MB) -> flags[0]=0 in practice;
// bf16/MFMA branches kept only as dtype insurance.
// ---------------------------------------------------------------------------
__global__ __launch_bounds__(256) void det_k(const u32* __restrict__ x32,
                                             const u32* __restrict__ ei32,
                                             int* __restrict__ flags)
{
    __shared__ int cnt;
    __shared__ int orv;
    if (threadIdx.x == 0) { cnt = 0; orv = 0; }
    __syncthreads();
    u32 w = x32[threadIdx.x];
    int e = (int)((w >> 7) & 0xffu);          // exponent field of low-u16-as-bf16
    if (e >= 112 && e <= 136) atomicAdd(&cnt, 1);
    if (threadIdx.x < 32) {
        if (ei32[2 * threadIdx.x + 1] != 0u) atomicOr(&orv, 1);
    }
    __syncthreads();
    if (threadIdx.x == 0) {
        flags[0] = (cnt >= 128) ? 1 : 0;
        flags[1] = (orv == 0) ? 1 : 0;
    }
}

// edge index accessors (ei32 = edge_index buffer viewed as u32)
__device__ __forceinline__ int src_at(const u32* ei32, int t, int E, int fI) {
    return (int)(fI ? ei32[2 * t] : ei32[t]);
}
__device__ __forceinline__ int dst_at(const u32* ei32, int t, int E, int fI) {
    return (int)(fI ? ei32[2 * (E + t)] : ei32[E + t]);
}

// ---------------------------------------------------------------------------
// Convert all small weights/biases -> fp32 in workspace, plus W1 in bf16
// MFMA B-fragment order (used only if input ever arrives as bf16).
// ---------------------------------------------------------------------------
__global__ __launch_bounds__(256) void prep_weights(
    const void* __restrict__ W1, const void* __restrict__ W2,
    const void* __restrict__ fcw, const void* __restrict__ cw1,
    const void* __restrict__ cw2, const void* __restrict__ b1,
    const void* __restrict__ b2, const void* __restrict__ fcb,
    const void* __restrict__ cb1, const void* __restrict__ cb2,
    const int* __restrict__ flags,
    float* __restrict__ w1f, float* __restrict__ w2f, float* __restrict__ fcwf,
    float* __restrict__ cw1f, float* __restrict__ cw2f, float* __restrict__ b1f,
    float* __restrict__ b2f, float* __restrict__ fcbf, float* __restrict__ cb1f,
    float* __restrict__ cb2f, u16* __restrict__ w1b)
{
    int fF = flags[0];
    int t = blockIdx.x * blockDim.x + threadIdx.x;
    if (t < 8192) { w1f[t] = ldw(W1, t, fF); return; }
    int u = t - 8192;
    if (u < 256)  { w2f[u]  = ldw(W2, u, fF);  return; }  u -= 256;
    if (u < 16)   { fcwf[u] = ldw(fcw, u, fF); return; }  u -= 16;
    if (u < 2048) { cw1f[u] = ldw(cw1, u, fF); return; }  u -= 2048;
    if (u < 16)   { cw2f[u] = ldw(cw2, u, fF); return; }  u -= 16;
    if (u < 16)   { b1f[u]  = ldw(b1, u, fF);  return; }  u -= 16;
    if (u < 16)   { b2f[u]  = ldw(b2, u, fF);  return; }  u -= 16;
    if (u < 1)    { fcbf[u] = ldw(fcb, u, fF); return; }  u -= 1;
    if (u < 16)   { cb1f[u] = ldw(cb1, u, fF); return; }  u -= 16;
    if (u < 1)    { cb2f[u] = ldw(cb2, u, fF); return; }  u -= 1;
    if (u < 8192) {
        int kb = u >> 9;           // K-block (16)
        int r  = (u >> 3) & 63;    // lane (64)
        int j  = u & 7;            // elem (8)
        w1b[u] = f2bf(ldw(W1, (kb * 32 + (r >> 4) * 8 + j) * 16 + (r & 15), fF));
    }
}

// ---------------------------------------------------------------------------
// Degree count (graph shared across batch -> computed once). deg pre-zeroed.
// ---------------------------------------------------------------------------
__global__ __launch_bounds__(256) void deg_k(const u32* __restrict__ ei32,
                                             const int* __restrict__ flags,
                                             int* __restrict__ deg, int E)
{
    int t = blockIdx.x * blockDim.x + threadIdx.x;
    if (t >= E) return;
    int d = dst_at(ei32, t, E, flags[1]);
    if ((unsigned)d < (unsigned)N_) atomicAdd(&deg[d], 1);
}

// ---------------------------------------------------------------------------
// Single-block exclusive scan over deg[5000] -> rowptr/cursor, plus dinv.
// ---------------------------------------------------------------------------
__global__ __launch_bounds__(1024) void scan_k(const int* __restrict__ deg,
                                               int* __restrict__ rowptr,
                                               int* __restrict__ cursor,
                                               float* __restrict__ dinv)
{
    __shared__ int ssum[1024];
    int t = threadIdx.x;
    int base = t * 5;
    int loc[5];
    int run = 0;
#pragma unroll
    for (int i = 0; i < 5; i++) {
        int idx = base + i;
        int v = (idx < N_) ? deg[idx] : 0;
        loc[i] = run;
        run += v;
    }
    ssum[t] = run;
    __syncthreads();
    for (int offs = 1; offs < 1024; offs <<= 1) {
        int v = (t >= offs) ? ssum[t - offs] : 0;
        __syncthreads();
        ssum[t] += v;
        __syncthreads();
    }
    int exclusive = ssum[t] - run;
#pragma unroll
    for (int i = 0; i < 5; i++) {
        int idx = base + i;
        if (idx < N_) {
            int rp = exclusive + loc[i];
            rowptr[idx] = rp;
            cursor[idx] = rp;
            dinv[idx] = 1.0f / sqrtf((float)deg[idx] + 1.0f);  // +1 self loop
        }
    }
    if (t == 1023) rowptr[N_] = ssum[1023];
}

// ---------------------------------------------------------------------------
// CSR fill: csr[rowptr[d] ...] = list of src nodes with an edge into d.
// ---------------------------------------------------------------------------
__global__ __launch_bounds__(256) void fill_k(const u32* __restrict__ ei32,
                                              const int* __restrict__ flags,
                                              int* __restrict__ cursor,
                                              int* __restrict__ csr, int E)
{
    int t = blockIdx.x * blockDim.x + threadIdx.x;
    if (t >= E) return;
    int fI = flags[1];
    int s = src_at(ei32, t, E, fI);
    int d = dst_at(ei32, t, E, fI);
    if ((unsigned)d >= (unsigned)N_) return;
    if ((unsigned)s >= (unsigned)N_) s = 0;    // guard (only if detection wrong)
    int pos = atomicAdd(&cursor[d], 1);
    if ((unsigned)pos < (unsigned)E) csr[pos] = s;
}

// ---------------------------------------------------------------------------
// GEMM1 (K-split): block b -> rows [ (b>>1)*64 .. +64 ), f-half (b&1)*256.
// 2500 blocks (9.8/CU; r8's 1250 was grid-limited at 39% occupancy) each
// write fp32 partials (pre-dinv) to pbuf[half][row][16]; greduce_k sums.
// fp32 path: LDS-staged x (pitch 65, 2-way banks both phases) + weights via
// readfirstlane-uniform pointer -> scalar s_loads + SGPR-operand v_fma
// (the r6/r7 VMEM-weight bottleneck fix, verified r8: 111 -> ~72us).
// bf16 path: register-resident MFMA on this half's 8 K-blocks (insurance).
// ---------------------------------------------------------------------------
__global__ __launch_bounds__(256, 6) void gemm1_k(const void* __restrict__ xraw,
                                                  const float* __restrict__ w1f,
                                                  const u16* __restrict__ w1b,
                                                  const int* __restrict__ flags,
                                                  float* __restrict__ pbuf)
{
    __shared__ float smem[4352];        // [64 x pitch65] / [4][64][17]
    const int t    = threadIdx.x;
    const int lane = t & 63;
    const int wv   = t >> 6;            // 0..3
    const int half = blockIdx.x & 1;    // f-half: [half*256, half*256+256)
    const int row0 = (blockIdx.x >> 1) * 64;
    const int fbase = half * 256;
    const int fF   = flags[0];
    float* pb = pbuf + (size_t)half * NT * 16;

    if (fF) {
        // ---- MFMA path (bf16 input; dead for fp32 harness) ----
        const u16* xb = (const u16*)xraw;
        bf16x8 bfr[8];
#pragma unroll
        for (int kb = 0; kb < 8; kb++)
            bfr[kb] = *(const bf16x8*)(w1b + (half * 8 + kb) * 512 + lane * 8);

        f32x4 acc = {0.0f, 0.0f, 0.0f, 0.0f};
        const u16* xr = xb + (size_t)(row0 + wv * 16 + (lane & 15)) * F_
                           + fbase + (lane >> 4) * 8;
#pragma unroll
        for (int kb = 0; kb < 8; kb++) {
            bf16x8 a = *(const bf16x8*)(xr + kb * 32);
            acc = __builtin_amdgcn_mfma_f32_16x16x32_bf16(a, bfr[kb], acc, 0, 0, 0);
        }
#pragma unroll
        for (int i = 0; i < 4; i++) {
            int grow = row0 + wv * 16 + (lane >> 4) * 4 + i;
            pb[(size_t)grow * 16 + (lane & 15)] = acc[i];
        }
        return;
    }

    // ---- fp32 path: LDS-staged x + SCALAR weight loads ----
    float acc[16];
#pragma unroll
    for (int k = 0; k < 16; k++) acc[k] = 0.0f;

    const int wvu = __builtin_amdgcn_readfirstlane(wv);

    for (int c = 0; c < 4; c++) {       // 4 chunks of 64 features in this half
        __syncthreads();
        const float* xf = (const float*)xraw + fbase + c * 64;
#pragma unroll
        for (int i = 0; i < 4; i++) {
            int u = i * 256 + t;            // 0..1023
            int r = u >> 4, c4 = u & 15;    // 16 float4 per row
            float4 v = *(const float4*)(xf + (size_t)(row0 + r) * F_ + c4 * 4);
            float* dp = &smem[r * 65 + c4 * 4];
            dp[0] = v.x; dp[1] = v.y; dp[2] = v.z; dp[3] = v.w;
        }
        __syncthreads();
        const float* xr = &smem[lane * 65 + wvu * 16];
        const float* wr = w1f + (fbase + c * 64 + wvu * 16) * 16;   // uniform
#pragma unroll
        for (int f = 0; f < 16; f++) {
            float xv = xr[f];
#pragma unroll
            for (int k = 0; k < 16; k++) acc[k] += xv * wr[f * 16 + k];
        }
    }

    __syncthreads();
    float (*red)[64][17] = (float (*)[64][17])smem;
#pragma unroll
    for (int k = 0; k < 16; k++) red[wv][lane][k] = acc[k];
    __syncthreads();

    int r  = t >> 2;
    int kc = (t & 3) * 4;
    float4 o;
    o.x = red[0][r][kc+0] + red[1][r][kc+0] + red[2][r][kc+0] + red[3][r][kc+0];
    o.y = red[0][r][kc+1] + red[1][r][kc+1] + red[2][r][kc+1] + red[3][r][kc+1];
    o.z = red[0][r][kc+2] + red[1][r][kc+2] + red[2][r][kc+2] + red[3][r][kc+2];
    o.w = red[0][r][kc+3] + red[1][r][kc+3] + red[2][r][kc+3] + red[3][r][kc+3];
    *(float4*)(pb + (size_t)(row0 + r) * 16 + kc) = o;
}

// ---------------------------------------------------------------------------
// Sum the two K-halves, apply dinv, emit bf16 H' in [n][16b][16k] layout
// (so agg gathers are dense 512B segments). Coalesced float4 reads.
// ---------------------------------------------------------------------------
__global__ __launch_bounds__(256) void greduce_k(const float* __restrict__ pbuf,
                                                 const float* __restrict__ dinv,
                                                 u16* __restrict__ out)
{
    int t = blockIdx.x * blockDim.x + threadIdx.x;   // 0 .. NT*16/4-1
    if (t >= NT * 4) return;
    int i = t * 4;
    int row = i >> 4;
    int kc  = i & 15;           // 0,4,8,12
    float4 a = *(const float4*)(pbuf + i);
    float4 b = *(const float4*)(pbuf + (size_t)NT * 16 + i);
    int n  = row % N_;
    int bb = row / N_;
    float s = dinv[n];
    union { uint2 u; u16 h[4]; } o;
    o.h[0] = f2bf((a.x + b.x) * s);
    o.h[1] = f2bf((a.y + b.y) * s);
    o.h[2] = f2bf((a.z + b.z) * s);
    o.h[3] = f2bf((a.w + b.w) * s);
    *(uint2*)(out + (size_t)n * 256 + bb * 16 + kc) = o.u;
}

// ---------------------------------------------------------------------------
// Aggregation 1 + fused GEMM2. One block per NODE d, covering all 16 batches
// (tid = b*16 + k). H layout [n][b][k]: each edge gather is one dense 512B
// segment read by the whole block (fully coalesced); csr read once per node.
//   x1[b,k]    = relu(dinv[d]*(H'[d,b,k] + sum_{s->d} H'[s,b,k]) + b1[k])
//   H2'[d,b,k] = dinv[d] * sum_j x1[b,j] * W2[j,k]      (16-lane shfl)
// ---------------------------------------------------------------------------
__global__ __launch_bounds__(256) void agg1_k(const u16* __restrict__ h,
                                              const int* __restrict__ rowptr,
                                              const int* __restrict__ csr,
                                              const float* __restrict__ dinv,
                                              const float* __restrict__ b1f,
                                              const float* __restrict__ w2f,
                                              u16* __restrict__ out)
{
    int d   = blockIdx.x;          // 0..N_-1
    int tid = threadIdx.x;         // b*16 + k
    int k   = tid & 15;
    float acc = bf2f(h[(size_t)d * 256 + tid]);   // self loop
    int e0 = rowptr[d], e1 = rowptr[d + 1];
    for (int base = e0; base < e1; base += 8) {
        int idx[8];
#pragma unroll
        for (int j = 0; j < 8; j++) {
            int e = base + j;
            idx[j] = csr[e < e1 ? e : e0];
        }
        float v[8];
#pragma unroll
        for (int j = 0; j < 8; j++) v[j] = bf2f(h[(size_t)idx[j] * 256 + tid]);
#pragma unroll
        for (int j = 0; j < 8; j++) if (base + j < e1) acc += v[j];
    }
    float dv = dinv[d];
    float x1 = fmaxf(acc * dv + b1f[k], 0.0f);
    // fused 16x16 GEMM2 (X1 stays fp32)
    float h2 = 0.0f;
#pragma unroll
    for (int j = 0; j < 16; j++) {
        float xj = __shfl(x1, j, 16);
        h2 += xj * w2f[j * 16 + k];
    }
    out[(size_t)d * 256 + tid] = f2bf(h2 * dv);
}

// ---------------------------------------------------------------------------
// Aggregation 2 + fused node head. Same per-node block structure.
//   x2[b,k] = relu(dinv[d]*(H2'[d,b,k] + sum H2'[s,b,k]) + b2[k])
//   nl[b,d] = sum_k x2[b,k]*fc_w[k] + fc_b     (16-lane shfl reduction)
// ---------------------------------------------------------------------------
__global__ __launch_bounds__(256) void agg2_k(const u16* __restrict__ h,
                                              const int* __restrict__ rowptr,
                                              const int* __restrict__ csr,
                                              const float* __restrict__ dinv,
                                              const float* __restrict__ b2f,
                                              const float* __restrict__ fcwf,
                                              const float* __restrict__ fcbf,
                                              float* __restrict__ nl)
{
    int d   = blockIdx.x;
    int tid = threadIdx.x;
    int k   = tid & 15;
    int b   = tid >> 4;
    float acc = bf2f(h[(size_t)d * 256 + tid]);
    int e0 = rowptr[d], e1 = rowptr[d + 1];
    for (int base = e0; base < e1; base += 8) {
        int idx[8];
#pragma unroll
        for (int j = 0; j < 8; j++) {
            int e = base + j;
            idx[j] = csr[e < e1 ? e : e0];
        }
        float v[8];
#pragma unroll
        for (int j = 0; j < 8; j++) v[j] = bf2f(h[(size_t)idx[j] * 256 + tid]);
#pragma unroll
        for (int j = 0; j < 8; j++) if (base + j < e1) acc += v[j];
    }
    float x2 = fmaxf(acc * dinv[d] + b2f[k], 0.0f);
    float p = x2 * fcwf[k];
    p += __shfl_xor(p, 8, 16);
    p += __shfl_xor(p, 4, 16);
    p += __shfl_xor(p, 2, 16);
    p += __shfl_xor(p, 1, 16);
    if (k == 0) nl[b * N_ + d] = p + fcbf[0];
}

// ---------------------------------------------------------------------------
// Column MLP: cl[b,c] = (relu(cf[b,c,:] @ cw1 + cb1)) @ cw2 + cb2
// (weight addresses here are thread-independent -> already scalar loads)
// ---------------------------------------------------------------------------
__global__ __launch_bounds__(256) void col_k(const void* __restrict__ cfraw,
                                             const float* __restrict__ cw1f,
                                             const float* __restrict__ cb1f,
                                             const float* __restrict__ cw2f,
                                             const float* __restrict__ cb2f,
                                             const int* __restrict__ flags,
                                             float* __restrict__ cl)
{
    int t = blockIdx.x * blockDim.x + threadIdx.x;
    if (t >= B_ * C_) return;
    float acc[16];
#pragma unroll
    for (int k = 0; k < 16; k++) acc[k] = cb1f[k];
    if (flags[0]) {
        const u16* r = (const u16*)cfraw + (size_t)t * FC_;
        for (int f = 0; f < FC_; f += 8) {
            uint4 pk = *(const uint4*)(r + f);
            u32 q[4] = {pk.x, pk.y, pk.z, pk.w};
#pragma unroll
            for (int j = 0; j < 4; j++) {
                float v0 = bf2f((u16)(q[j] & 0xffffu));
                float v1 = bf2f((u16)(q[j] >> 16));
                const float* w0 = cw1f + (f + 2 * j) * 16;
#pragma unroll
                for (int k = 0; k < 16; k++) acc[k] += v0 * w0[k];
#pragma unroll
                for (int k = 0; k < 16; k++) acc[k] += v1 * w0[16 + k];
            }
        }
    } else {
        const float* r = (const float*)cfraw + (size_t)t * FC_;
        for (int f = 0; f < FC_; f += 4) {
            float4 a = *(const float4*)(r + f);
            float v[4] = {a.x, a.y, a.z, a.w};
#pragma unroll
            for (int j = 0; j < 4; j++) {
                const float* w0 = cw1f + (f + j) * 16;
#pragma unroll
                for (int k = 0; k < 16; k++) acc[k] += v[j] * w0[k];
            }
        }
    }
    float s = cb2f[0];
#pragma unroll
    for (int k = 0; k < 16; k++) s += fmaxf(acc[k], 0.0f) * cw2f[k];
    cl[t] = s;
}

// ---------------------------------------------------------------------------
// Join: out[b, n*C + c] = nl[b,n] + cl[b,c]; output dtype follows input dtype
// ---------------------------------------------------------------------------
__global__ __launch_bounds__(256) void join_k(const float* __restrict__ nl,
                                              const float* __restrict__ cl,
                                              const int* __restrict__ flags,
                                              void* __restrict__ outraw)
{
    int t = blockIdx.x * blockDim.x + threadIdx.x;
    if (t >= NT * C_ / 8) return;
    int g  = t >> 3;          // b*N + n
    int c0 = (t & 7) * 8;
    int b  = g / N_;
    float nv = nl[g];
    const float* c = cl + b * C_ + c0;
    float4 a0 = *(const float4*)c;
    float4 a1 = *(const float4*)(c + 4);
    float v[8] = {a0.x, a0.y, a0.z, a0.w, a1.x, a1.y, a1.z, a1.w};
#pragma unroll
    for (int i = 0; i < 8; i++) v[i] += nv;
    size_t idx = (size_t)g * C_ + c0;
    if (flags[0]) {
        union { uint4 u; u16 h[8]; } pkv;
#pragma unroll
        for (int i = 0; i < 8; i++) pkv.h[i] = f2bf(v[i]);
        *(uint4*)((u16*)outraw + idx) = pkv.u;
    } else {
        float* o = (float*)outraw + idx;
        *(float4*)o       = make_float4(v[0], v[1], v[2], v[3]);
        *(float4*)(o + 4) = make_float4(v[4], v[5], v[6], v[7]);
    }
}

// ---------------------------------------------------------------------------
extern "C" void kernel_launch(void* const* d_in, const int* in_sizes, int n_in,
                              void* d_out, int out_size, void* d_ws, size_t ws_size,
                              hipStream_t stream)
{
    const void* x    = d_in[0];              // node_features  [B,N,F]
    const void* cf   = d_in[1];              // col_features   [B,C,FC]
    const u32*  ei32 = (const u32*)d_in[2];  // edge_index     [2,E] int32 or int64
    const void* W1   = d_in[3];
    const void* b1   = d_in[4];
    const void* W2   = d_in[5];
    const void* b2   = d_in[6];
    const void* fcw  = d_in[7];
    const void* fcb  = d_in[8];
    const void* cw1  = d_in[9];
    const void* cb1  = d_in[10];
    const void* cw2  = d_in[11];
    const void* cb2  = d_in[12];

    const int E = in_sizes[2] / 2;

    // workspace layout (~17 MB)
    char* base = (char*)d_ws;
    size_t off = 0;
    auto alloc = [&](size_t bytes) -> void* {
        void* p = base + off;
        off = (off + bytes + 255) & ~(size_t)255;
        return p;
    };
    int*   flags  = (int*)alloc(2 * 4);
    float* w1f  = (float*)alloc(8192 * 4);
    u16*   w1b  = (u16*)alloc(8192 * 2);    // W1 bf16, MFMA B-fragment order
    float* w2f  = (float*)alloc(256 * 4);
    float* fcwf = (float*)alloc(16 * 4);
    float* cw1f = (float*)alloc(2048 * 4);
    float* cw2f = (float*)alloc(16 * 4);
    float* b1f  = (float*)alloc(16 * 4);
    float* b2f  = (float*)alloc(16 * 4);
    float* fcbf = (float*)alloc(4);
    float* cb1f = (float*)alloc(16 * 4);
    float* cb2f = (float*)alloc(4);
    int*   deg    = (int*)alloc((size_t)N_ * 4);
    int*   rowptr = (int*)alloc((size_t)(N_ + 1) * 4);
    int*   cursor = (int*)alloc((size_t)N_ * 4);
    float* dinv   = (float*)alloc((size_t)N_ * 4);
    int*   csr    = (int*)alloc((size_t)E * 4);
    float* pbuf = (float*)alloc((size_t)2 * NT * 16 * 4); // gemm1 K-partials
    u16*   bufA = (u16*)alloc((size_t)NT * 16 * 2);   // H'  (bf16, [n][b][k])
    u16*   bufB = (u16*)alloc((size_t)NT * 16 * 2);   // H2' (bf16, [n][b][k])
    float* nl   = (float*)alloc((size_t)NT * 4);
    float* cl   = (float*)alloc((size_t)B_ * C_ * 4);

    det_k<<<1, 256, 0, stream>>>((const u32*)x, ei32, flags);
    hipMemsetAsync(deg, 0, (size_t)N_ * 4, stream);
    prep_weights<<<(10578 + 8192 + 255) / 256, 256, 0, stream>>>(
        W1, W2, fcw, cw1, cw2, b1, b2, fcb, cb1, cb2, flags,
        w1f, w2f, fcwf, cw1f, cw2f, b1f, b2f, fcbf, cb1f, cb2f, w1b);
    deg_k<<<(E + 255) / 256, 256, 0, stream>>>(ei32, flags, deg, E);
    scan_k<<<1, 1024, 0, stream>>>(deg, rowptr, cursor, dinv);
    fill_k<<<(E + 255) / 256, 256, 0, stream>>>(ei32, flags, cursor, csr, E);

    gemm1_k<<<2 * (NT / 64), 256, 0, stream>>>(x, w1f, w1b, flags, pbuf);
    greduce_k<<<(NT * 4 + 255) / 256, 256, 0, stream>>>(pbuf, dinv, bufA);
    agg1_k<<<N_, 256, 0, stream>>>(bufA, rowptr, csr, dinv, b1f, w2f, bufB);
    agg2_k<<<N_, 256, 0, stream>>>(bufB, rowptr, csr, dinv, b2f, fcwf, fcbf, nl);
    col_k<<<(B_ * C_ + 255) / 256, 256, 0, stream>>>(cf, cw1f, cb1f, cw2f, cb2f, flags, cl);
    join_k<<<(NT * C_ / 8 + 255) / 256, 256, 0, stream>>>(nl, cl, flags, d_out);
}

// Round 10
// 362.829 us; speedup vs baseline: 1.0100x; 1.0100x over previous
//
#include <hip/hip_runtime.h>
#include <hip/hip_bf16.h>

typedef unsigned short u16;
typedef unsigned int   u32;
typedef __attribute__((ext_vector_type(8))) short bf16x8;   // 8 bf16 = 4 VGPR
typedef __attribute__((ext_vector_type(4))) float f32x4;    // MFMA accum

#define B_  16
#define N_  5000
#define F_  512
#define C_  64
#define FC_ 128
#define NT  (B_ * N_)   // 80000 total nodes

__device__ __forceinline__ float bf2f(u16 h) {
    return __uint_as_float(((u32)h) << 16);
}
__device__ __forceinline__ u16 f2bf(float f) {
    union { __hip_bfloat16 h; u16 s; } c; c.h = __float2bfloat16(f); return c.s;
}
// dtype-flexible scalar weight load (fF: 1 = bf16 data, 0 = fp32 data)
__device__ __forceinline__ float ldw(const void* p, int i, int fF) {
    return fF ? bf2f(((const u16*)p)[i]) : ((const float*)p)[i];
}

// ---------------------------------------------------------------------------
// Detector: flags[0] = 1 if float tensors are bf16 (else fp32)
//           flags[1] = 1 if edge_index is int64 (else int32)
// NOTE (r7): harness inputs are fp32 -> flags[0]=0 in practice.
// ---------------------------------------------------------------------------
__global__ __launch_bounds__(256) void det_k(const u32* __restrict__ x32,
                                             const u32* __restrict__ ei32,
                                             int* __restrict__ flags)
{
    __shared__ int cnt;
    __shared__ int orv;
    if (threadIdx.x == 0) { cnt = 0; orv = 0; }
    __syncthreads();
    u32 w = x32[threadIdx.x];
    int e = (int)((w >> 7) & 0xffu);          // exponent field of low-u16-as-bf16
    if (e >= 112 && e <= 136) atomicAdd(&cnt, 1);
    if (threadIdx.x < 32) {
        if (ei32[2 * threadIdx.x + 1] != 0u) atomicOr(&orv, 1);
    }
    __syncthreads();
    if (threadIdx.x == 0) {
        flags[0] = (cnt >= 128) ? 1 : 0;
        flags[1] = (orv == 0) ? 1 : 0;
    }
}

// edge index accessors (ei32 = edge_index buffer viewed as u32)
__device__ __forceinline__ int src_at(const u32* ei32, int t, int E, int fI) {
    return (int)(fI ? ei32[2 * t] : ei32[t]);
}
__device__ __forceinline__ int dst_at(const u32* ei32, int t, int E, int fI) {
    return (int)(fI ? ei32[2 * (E + t)] : ei32[E + t]);
}

// ---------------------------------------------------------------------------
// Convert all small weights/biases -> fp32 in workspace, plus W1 in bf16
// MFMA B-fragment order (used only if input ever arrives as bf16).
// ---------------------------------------------------------------------------
__global__ __launch_bounds__(256) void prep_weights(
    const void* __restrict__ W1, const void* __restrict__ W2,
    const void* __restrict__ fcw, const void* __restrict__ cw1,
    const void* __restrict__ cw2, const void* __restrict__ b1,
    const void* __restrict__ b2, const void* __restrict__ fcb,
    const void* __restrict__ cb1, const void* __restrict__ cb2,
    const int* __restrict__ flags,
    float* __restrict__ w1f, float* __restrict__ w2f, float* __restrict__ fcwf,
    float* __restrict__ cw1f, float* __restrict__ cw2f, float* __restrict__ b1f,
    float* __restrict__ b2f, float* __restrict__ fcbf, float* __restrict__ cb1f,
    float* __restrict__ cb2f, u16* __restrict__ w1b)
{
    int fF = flags[0];
    int t = blockIdx.x * blockDim.x + threadIdx.x;
    if (t < 8192) { w1f[t] = ldw(W1, t, fF); return; }
    int u = t - 8192;
    if (u < 256)  { w2f[u]  = ldw(W2, u, fF);  return; }  u -= 256;
    if (u < 16)   { fcwf[u] = ldw(fcw, u, fF); return; }  u -= 16;
    if (u < 2048) { cw1f[u] = ldw(cw1, u, fF); return; }  u -= 2048;
    if (u < 16)   { cw2f[u] = ldw(cw2, u, fF); return; }  u -= 16;
    if (u < 16)   { b1f[u]  = ldw(b1, u, fF);  return; }  u -= 16;
    if (u < 16)   { b2f[u]  = ldw(b2, u, fF);  return; }  u -= 16;
    if (u < 1)    { fcbf[u] = ldw(fcb, u, fF); return; }  u -= 1;
    if (u < 16)   { cb1f[u] = ldw(cb1, u, fF); return; }  u -= 16;
    if (u < 1)    { cb2f[u] = ldw(cb2, u, fF); return; }  u -= 1;
    if (u < 8192) {
        int kb = u >> 9;           // K-block (16)
        int r  = (u >> 3) & 63;    // lane (64)
        int j  = u & 7;            // elem (8)
        w1b[u] = f2bf(ldw(W1, (kb * 32 + (r >> 4) * 8 + j) * 16 + (r & 15), fF));
    }
}

// ---------------------------------------------------------------------------
// Degree count (graph shared across batch -> computed once). deg pre-zeroed.
// ---------------------------------------------------------------------------
__global__ __launch_bounds__(256) void deg_k(const u32* __restrict__ ei32,
                                             const int* __restrict__ flags,
                                             int* __restrict__ deg, int E)
{
    int t = blockIdx.x * blockDim.x + threadIdx.x;
    if (t >= E) return;
    int d = dst_at(ei32, t, E, flags[1]);
    if ((unsigned)d < (unsigned)N_) atomicAdd(&deg[d], 1);
}

// ---------------------------------------------------------------------------
// Single-block exclusive scan over deg[5000] -> rowptr/cursor, plus dinv.
// ---------------------------------------------------------------------------
__global__ __launch_bounds__(1024) void scan_k(const int* __restrict__ deg,
                                               int* __restrict__ rowptr,
                                               int* __restrict__ cursor,
                                               float* __restrict__ dinv)
{
    __shared__ int ssum[1024];
    int t = threadIdx.x;
    int base = t * 5;
    int loc[5];
    int run = 0;
#pragma unroll
    for (int i = 0; i < 5; i++) {
        int idx = base + i;
        int v = (idx < N_) ? deg[idx] : 0;
        loc[i] = run;
        run += v;
    }
    ssum[t] = run;
    __syncthreads();
    for (int offs = 1; offs < 1024; offs <<= 1) {
        int v = (t >= offs) ? ssum[t - offs] : 0;
        __syncthreads();
        ssum[t] += v;
        __syncthreads();
    }
    int exclusive = ssum[t] - run;
#pragma unroll
    for (int i = 0; i < 5; i++) {
        int idx = base + i;
        if (idx < N_) {
            int rp = exclusive + loc[i];
            rowptr[idx] = rp;
            cursor[idx] = rp;
            dinv[idx] = 1.0f / sqrtf((float)deg[idx] + 1.0f);  // +1 self loop
        }
    }
    if (t == 1023) rowptr[N_] = ssum[1023];
}

// ---------------------------------------------------------------------------
// CSR fill: csr[rowptr[d] ...] = list of src nodes with an edge into d.
// ---------------------------------------------------------------------------
__global__ __launch_bounds__(256) void fill_k(const u32* __restrict__ ei32,
                                              const int* __restrict__ flags,
                                              int* __restrict__ cursor,
                                              int* __restrict__ csr, int E)
{
    int t = blockIdx.x * blockDim.x + threadIdx.x;
    if (t >= E) return;
    int fI = flags[1];
    int s = src_at(ei32, t, E, fI);
    int d = dst_at(ei32, t, E, fI);
    if ((unsigned)d >= (unsigned)N_) return;
    if ((unsigned)s >= (unsigned)N_) s = 0;    // guard (only if detection wrong)
    int pos = atomicAdd(&cursor[d], 1);
    if ((unsigned)pos < (unsigned)E) csr[pos] = s;
}

// ---------------------------------------------------------------------------
// GEMM1: H'[n][b][k] = dinv[n] * sum_f x[b,n,f] * W1[f,k]
// BARRIER-FREE per-wave pipeline (r9 post-mortem: 2-phase block barrier is
// the structural limit; occupancy/K-split were neutral).
//   Wave wv owns f-span [wv*128, wv*128+128), 8 sub-chunks of 16 features.
//   Per chunk: LOAD(c+1)->regs (issued early, hides HBM latency under FMA)
//              COMPUTE(c) from this wave's private LDS tile
//              STORE(c+1) regs->LDS (other buffer)
//   No __syncthreads in the K-loop (wave only reads what it wrote; waitcnts
//   are per-wave and compiler-managed). Weights stay readfirstlane-uniform
//   -> scalar s_loads + SGPR-operand v_fma (r8's proven fix).
//   LDS tile: [64 rows][pad 18] per wave per buf (float2 granularity, 8B
//   aligned; write ~2-way, read 4-way banks = near-free). 36.9KB/block.
//   Staging: 4 lanes/row -> 64B contiguous segments (semi-coalesced).
// One final barrier pair for the cross-wave K-reduction ([4][64][17] view).
// bf16 path: register-resident MFMA (dtype insurance, r8 version).
// Output layout [n][16b][16k] so agg gathers are dense 512B segments.
// ---------------------------------------------------------------------------
__global__ __launch_bounds__(256, 4) void gemm1_k(const void* __restrict__ xraw,
                                                  const float* __restrict__ w1f,
                                                  const u16* __restrict__ w1b,
                                                  const float* __restrict__ dinv,
                                                  const int* __restrict__ flags,
                                                  u16* __restrict__ out)
{
    __shared__ float smem[9216];        // 4 waves x 2 bufs x (64x18) floats
    const int t    = threadIdx.x;
    const int lane = t & 63;
    const int wv   = t >> 6;            // 0..3
    const int row0 = blockIdx.x * 64;   // NT = 1250*64 exactly
    const int fF   = flags[0];

    if (fF) {
        // ---- MFMA path (bf16 input; dead for fp32 harness) ----
        const u16* xb = (const u16*)xraw;
        bf16x8 bfr[16];
#pragma unroll
        for (int kb = 0; kb < 16; kb++)
            bfr[kb] = *(const bf16x8*)(w1b + kb * 512 + lane * 8);

        f32x4 acc = {0.0f, 0.0f, 0.0f, 0.0f};
        const u16* xr = xb + (size_t)(row0 + wv * 16 + (lane & 15)) * F_
                           + (lane >> 4) * 8;
#pragma unroll
        for (int kb = 0; kb < 16; kb++) {
            bf16x8 a = *(const bf16x8*)(xr + kb * 32);
            acc = __builtin_amdgcn_mfma_f32_16x16x32_bf16(a, bfr[kb], acc, 0, 0, 0);
        }
#pragma unroll
        for (int i = 0; i < 4; i++) {
            int grow = row0 + wv * 16 + (lane >> 4) * 4 + i;
            int n  = grow % N_;
            int bb = grow / N_;
            out[(size_t)n * 256 + bb * 16 + (lane & 15)] = f2bf(acc[i] * dinv[n]);
        }
        return;
    }

    // ---- fp32 path: barrier-free per-wave pipeline ----
    float acc[16];
#pragma unroll
    for (int k = 0; k < 16; k++) acc[k] = 0.0f;

    const int wvu  = __builtin_amdgcn_readfirstlane(wv);
    float* wt      = smem + wvu * 2304;      // this wave's 2 bufs (1152 each)
    const float* xf = (const float*)xraw;
    const int rsub = lane >> 2;              // 0..15 (row sub-index)
    const int slot = lane & 3;               // 16B slot within row

    float4 pre[4];
    auto g1_load = [&](int cc) {
#pragma unroll
        for (int i = 0; i < 4; i++) {
            int row = 16 * i + rsub;
            pre[i] = *(const float4*)(xf + (size_t)(row0 + row) * F_
                                      + wvu * 128 + cc * 16 + slot * 4);
        }
    };
    auto g1_store = [&](int bb) {
#pragma unroll
        for (int i = 0; i < 4; i++) {
            int row = 16 * i + rsub;
            float* dp = wt + bb * 1152 + row * 18 + slot * 4;
            *(float2*)dp       = make_float2(pre[i].x, pre[i].y);
            *(float2*)(dp + 2) = make_float2(pre[i].z, pre[i].w);
        }
    };

    g1_load(0);
    g1_store(0);
    for (int c = 0; c < 8; c++) {
        if (c < 7) g1_load(c + 1);           // issue next-chunk loads early
        const float* xrow = wt + (c & 1) * 1152 + lane * 18;
        const float* wr   = w1f + (wvu * 128 + c * 16) * 16;   // uniform
#pragma unroll
        for (int f = 0; f < 16; f += 2) {
            float2 xv = *(const float2*)(xrow + f);
#pragma unroll
            for (int k = 0; k < 16; k++) acc[k] += xv.x * wr[f * 16 + k];
#pragma unroll
            for (int k = 0; k < 16; k++) acc[k] += xv.y * wr[(f + 1) * 16 + k];
        }
        if (c < 7) g1_store((c + 1) & 1);    // write-late (after compute)
    }

    // --- cross-wave K-reduction: smem as [4][64][17] ---
    __syncthreads();
    float (*red)[64][17] = (float (*)[64][17])smem;
#pragma unroll
    for (int k = 0; k < 16; k++) red[wv][lane][k] = acc[k];
    __syncthreads();

    int r  = t >> 2;
    int kc = (t & 3) * 4;
    int row = row0 + r;
    int n = row % N_;
    int b = row / N_;
    float s = dinv[n];
    union { uint2 u; u16 h[4]; } o;
#pragma unroll
    for (int k = 0; k < 4; k++) {
        float v = red[0][r][kc + k] + red[1][r][kc + k]
                + red[2][r][kc + k] + red[3][r][kc + k];
        o.h[k] = f2bf(v * s);
    }
    *(uint2*)(out + (size_t)n * 256 + b * 16 + kc) = o.u;
}

// ---------------------------------------------------------------------------
// Aggregation 1 + fused GEMM2. One block per NODE d, covering all 16 batches
// (tid = b*16 + k). H layout [n][b][k]: each edge gather is one dense 512B
// segment read by the whole block (fully coalesced); csr read once per node.
//   x1[b,k]    = relu(dinv[d]*(H'[d,b,k] + sum_{s->d} H'[s,b,k]) + b1[k])
//   H2'[d,b,k] = dinv[d] * sum_j x1[b,j] * W2[j,k]      (16-lane shfl)
// ---------------------------------------------------------------------------
__global__ __launch_bounds__(256) void agg1_k(const u16* __restrict__ h,
                                              const int* __restrict__ rowptr,
                                              const int* __restrict__ csr,
                                              const float* __restrict__ dinv,
                                              const float* __restrict__ b1f,
                                              const float* __restrict__ w2f,
                                              u16* __restrict__ out)
{
    int d   = blockIdx.x;          // 0..N_-1
    int tid = threadIdx.x;         // b*16 + k
    int k   = tid & 15;
    float acc = bf2f(h[(size_t)d * 256 + tid]);   // self loop
    int e0 = rowptr[d], e1 = rowptr[d + 1];
    for (int base = e0; base < e1; base += 8) {
        int idx[8];
#pragma unroll
        for (int j = 0; j < 8; j++) {
            int e = base + j;
            idx[j] = csr[e < e1 ? e : e0];
        }
        float v[8];
#pragma unroll
        for (int j = 0; j < 8; j++) v[j] = bf2f(h[(size_t)idx[j] * 256 + tid]);
#pragma unroll
        for (int j = 0; j < 8; j++) if (base + j < e1) acc += v[j];
    }
    float dv = dinv[d];
    float x1 = fmaxf(acc * dv + b1f[k], 0.0f);
    // fused 16x16 GEMM2 (X1 stays fp32)
    float h2 = 0.0f;
#pragma unroll
    for (int j = 0; j < 16; j++) {
        float xj = __shfl(x1, j, 16);
        h2 += xj * w2f[j * 16 + k];
    }
    out[(size_t)d * 256 + tid] = f2bf(h2 * dv);
}

// ---------------------------------------------------------------------------
// Aggregation 2 + fused node head. Same per-node block structure.
//   x2[b,k] = relu(dinv[d]*(H2'[d,b,k] + sum H2'[s,b,k]) + b2[k])
//   nl[b,d] = sum_k x2[b,k]*fc_w[k] + fc_b     (16-lane shfl reduction)
// ---------------------------------------------------------------------------
__global__ __launch_bounds__(256) void agg2_k(const u16* __restrict__ h,
                                              const int* __restrict__ rowptr,
                                              const int* __restrict__ csr,
                                              const float* __restrict__ dinv,
                                              const float* __restrict__ b2f,
                                              const float* __restrict__ fcwf,
                                              const float* __restrict__ fcbf,
                                              float* __restrict__ nl)
{
    int d   = blockIdx.x;
    int tid = threadIdx.x;
    int k   = tid & 15;
    int b   = tid >> 4;
    float acc = bf2f(h[(size_t)d * 256 + tid]);
    int e0 = rowptr[d], e1 = rowptr[d + 1];
    for (int base = e0; base < e1; base += 8) {
        int idx[8];
#pragma unroll
        for (int j = 0; j < 8; j++) {
            int e = base + j;
            idx[j] = csr[e < e1 ? e : e0];
        }
        float v[8];
#pragma unroll
        for (int j = 0; j < 8; j++) v[j] = bf2f(h[(size_t)idx[j] * 256 + tid]);
#pragma unroll
        for (int j = 0; j < 8; j++) if (base + j < e1) acc += v[j];
    }
    float x2 = fmaxf(acc * dinv[d] + b2f[k], 0.0f);
    float p = x2 * fcwf[k];
    p += __shfl_xor(p, 8, 16);
    p += __shfl_xor(p, 4, 16);
    p += __shfl_xor(p, 2, 16);
    p += __shfl_xor(p, 1, 16);
    if (k == 0) nl[b * N_ + d] = p + fcbf[0];
}

// ---------------------------------------------------------------------------
// Column MLP: cl[b,c] = (relu(cf[b,c,:] @ cw1 + cb1)) @ cw2 + cb2
// ---------------------------------------------------------------------------
__global__ __launch_bounds__(256) void col_k(const void* __restrict__ cfraw,
                                             const float* __restrict__ cw1f,
                                             const float* __restrict__ cb1f,
                                             const float* __restrict__ cw2f,
                                             const float* __restrict__ cb2f,
                                             const int* __restrict__ flags,
                                             float* __restrict__ cl)
{
    int t = blockIdx.x * blockDim.x + threadIdx.x;
    if (t >= B_ * C_) return;
    float acc[16];
#pragma unroll
    for (int k = 0; k < 16; k++) acc[k] = cb1f[k];
    if (flags[0]) {
        const u16* r = (const u16*)cfraw + (size_t)t * FC_;
        for (int f = 0; f < FC_; f += 8) {
            uint4 pk = *(const uint4*)(r + f);
            u32 q[4] = {pk.x, pk.y, pk.z, pk.w};
#pragma unroll
            for (int j = 0; j < 4; j++) {
                float v0 = bf2f((u16)(q[j] & 0xffffu));
                float v1 = bf2f((u16)(q[j] >> 16));
                const float* w0 = cw1f + (f + 2 * j) * 16;
#pragma unroll
                for (int k = 0; k < 16; k++) acc[k] += v0 * w0[k];
#pragma unroll
                for (int k = 0; k < 16; k++) acc[k] += v1 * w0[16 + k];
            }
        }
    } else {
        const float* r = (const float*)cfraw + (size_t)t * FC_;
        for (int f = 0; f < FC_; f += 4) {
            float4 a = *(const float4*)(r + f);
            float v[4] = {a.x, a.y, a.z, a.w};
#pragma unroll
            for (int j = 0; j < 4; j++) {
                const float* w0 = cw1f + (f + j) * 16;
#pragma unroll
                for (int k = 0; k < 16; k++) acc[k] += v[j] * w0[k];
            }
        }
    }
    float s = cb2f[0];
#pragma unroll
    for (int k = 0; k < 16; k++) s += fmaxf(acc[k], 0.0f) * cw2f[k];
    cl[t] = s;
}

// ---------------------------------------------------------------------------
// Join: out[b, n*C + c] = nl[b,n] + cl[b,c]; output dtype follows input dtype
// ---------------------------------------------------------------------------
__global__ __launch_bounds__(256) void join_k(const float* __restrict__ nl,
                                              const float* __restrict__ cl,
                                              const int* __restrict__ flags,
                                              void* __restrict__ outraw)
{
    int t = blockIdx.x * blockDim.x + threadIdx.x;
    if (t >= NT * C_ / 8) return;
    int g  = t >> 3;          // b*N + n
    int c0 = (t & 7) * 8;
    int b  = g / N_;
    float nv = nl[g];
    const float* c = cl + b * C_ + c0;
    float4 a0 = *(const float4*)c;
    float4 a1 = *(const float4*)(c + 4);
    float v[8] = {a0.x, a0.y, a0.z, a0.w, a1.x, a1.y, a1.z, a1.w};
#pragma unroll
    for (int i = 0; i < 8; i++) v[i] += nv;
    size_t idx = (size_t)g * C_ + c0;
    if (flags[0]) {
        union { uint4 u; u16 h[8]; } pkv;
#pragma unroll
        for (int i = 0; i < 8; i++) pkv.h[i] = f2bf(v[i]);
        *(uint4*)((u16*)outraw + idx) = pkv.u;
    } else {
        float* o = (float*)outraw + idx;
        *(float4*)o       = make_float4(v[0], v[1], v[2], v[3]);
        *(float4*)(o + 4) = make_float4(v[4], v[5], v[6], v[7]);
    }
}

// ---------------------------------------------------------------------------
extern "C" void kernel_launch(void* const* d_in, const int* in_sizes, int n_in,
                              void* d_out, int out_size, void* d_ws, size_t ws_size,
                              hipStream_t stream)
{
    const void* x    = d_in[0];              // node_features  [B,N,F]
    const void* cf   = d_in[1];              // col_features   [B,C,FC]
    const u32*  ei32 = (const u32*)d_in[2];  // edge_index     [2,E] int32 or int64
    const void* W1   = d_in[3];
    const void* b1   = d_in[4];
    const void* W2   = d_in[5];
    const void* b2   = d_in[6];
    const void* fcw  = d_in[7];
    const void* fcb  = d_in[8];
    const void* cw1  = d_in[9];
    const void* cb1  = d_in[10];
    const void* cw2  = d_in[11];
    const void* cb2  = d_in[12];

    const int E = in_sizes[2] / 2;

    // workspace layout (~6.3 MB)
    char* base = (char*)d_ws;
    size_t off = 0;
    auto alloc = [&](size_t bytes) -> void* {
        void* p = base + off;
        off = (off + bytes + 255) & ~(size_t)255;
        return p;
    };
    int*   flags  = (int*)alloc(2 * 4);
    float* w1f  = (float*)alloc(8192 * 4);
    u16*   w1b  = (u16*)alloc(8192 * 2);    // W1 bf16, MFMA B-fragment order
    float* w2f  = (float*)alloc(256 * 4);
    float* fcwf = (float*)alloc(16 * 4);
    float* cw1f = (float*)alloc(2048 * 4);
    float* cw2f = (float*)alloc(16 * 4);
    float* b1f  = (float*)alloc(16 * 4);
    float* b2f  = (float*)alloc(16 * 4);
    float* fcbf = (float*)alloc(4);
    float* cb1f = (float*)alloc(16 * 4);
    float* cb2f = (float*)alloc(4);
    int*   deg    = (int*)alloc((size_t)N_ * 4);
    int*   rowptr = (int*)alloc((size_t)(N_ + 1) * 4);
    int*   cursor = (int*)alloc((size_t)N_ * 4);
    float* dinv   = (float*)alloc((size_t)N_ * 4);
    int*   csr    = (int*)alloc((size_t)E * 4);
    u16*   bufA = (u16*)alloc((size_t)NT * 16 * 2);   // H'  (bf16, [n][b][k])
    u16*   bufB = (u16*)alloc((size_t)NT * 16 * 2);   // H2' (bf16, [n][b][k])
    float* nl   = (float*)alloc((size_t)NT * 4);
    float* cl   = (float*)alloc((size_t)B_ * C_ * 4);

    det_k<<<1, 256, 0, stream>>>((const u32*)x, ei32, flags);
    hipMemsetAsync(deg, 0, (size_t)N_ * 4, stream);
    prep_weights<<<(10578 + 8192 + 255) / 256, 256, 0, stream>>>(
        W1, W2, fcw, cw1, cw2, b1, b2, fcb, cb1, cb2, flags,
        w1f, w2f, fcwf, cw1f, cw2f, b1f, b2f, fcbf, cb1f, cb2f, w1b);
    deg_k<<<(E + 255) / 256, 256, 0, stream>>>(ei32, flags, deg, E);
    scan_k<<<1, 1024, 0, stream>>>(deg, rowptr, cursor, dinv);
    fill_k<<<(E + 255) / 256, 256, 0, stream>>>(ei32, flags, cursor, csr, E);

    gemm1_k<<<NT / 64, 256, 0, stream>>>(x, w1f, w1b, dinv, flags, bufA);
    agg1_k<<<N_, 256, 0, stream>>>(bufA, rowptr, csr, dinv, b1f, w2f, bufB);
    agg2_k<<<N_, 256, 0, stream>>>(bufB, rowptr, csr, dinv, b2f, fcwf, fcbf, nl);
    col_k<<<(B_ * C_ + 255) / 256, 256, 0, stream>>>(cf, cw1f, cb1f, cw2f, cb2f, flags, cl);
    join_k<<<(NT * C_ / 8 + 255) / 256, 256, 0, stream>>>(nl, cl, flags, d_out);
}

// Round 11
// 359.597 us; speedup vs baseline: 1.0191x; 1.0090x over previous
//
#include <hip/hip_runtime.h>
#include <hip/hip_bf16.h>

typedef unsigned short u16;
typedef unsigned int   u32;
typedef __attribute__((ext_vector_type(8))) short bf16x8;   // 8 bf16 = 4 VGPR
typedef __attribute__((ext_vector_type(4))) float f32x4;    // MFMA accum

#define B_  16
#define N_  5000
#define F_  512
#define C_  64
#define FC_ 128
#define NT  (B_ * N_)   // 80000 total nodes

__device__ __forceinline__ float bf2f(u16 h) {
    return __uint_as_float(((u32)h) << 16);
}
__device__ __forceinline__ u16 f2bf(float f) {
    union { __hip_bfloat16 h; u16 s; } c; c.h = __float2bfloat16(f); return c.s;
}
// dtype-flexible scalar weight load (fF: 1 = bf16 data, 0 = fp32 data)
__device__ __forceinline__ float ldw(const void* p, int i, int fF) {
    return fF ? bf2f(((const u16*)p)[i]) : ((const float*)p)[i];
}

// ---------------------------------------------------------------------------
// Detector: flags[0] = 1 if float tensors are bf16 (else fp32)
//           flags[1] = 1 if edge_index is int64 (else int32)
// NOTE (r7): harness inputs are fp32 -> flags[0]=0 in practice.
// ---------------------------------------------------------------------------
__global__ __launch_bounds__(256) void det_k(const u32* __restrict__ x32,
                                             const u32* __restrict__ ei32,
                                             int* __restrict__ flags)
{
    __shared__ int cnt;
    __shared__ int orv;
    if (threadIdx.x == 0) { cnt = 0; orv = 0; }
    __syncthreads();
    u32 w = x32[threadIdx.x];
    int e = (int)((w >> 7) & 0xffu);          // exponent field of low-u16-as-bf16
    if (e >= 112 && e <= 136) atomicAdd(&cnt, 1);
    if (threadIdx.x < 32) {
        if (ei32[2 * threadIdx.x + 1] != 0u) atomicOr(&orv, 1);
    }
    __syncthreads();
    if (threadIdx.x == 0) {
        flags[0] = (cnt >= 128) ? 1 : 0;
        flags[1] = (orv == 0) ? 1 : 0;
    }
}

// edge index accessors (ei32 = edge_index buffer viewed as u32)
__device__ __forceinline__ int src_at(const u32* ei32, int t, int E, int fI) {
    return (int)(fI ? ei32[2 * t] : ei32[t]);
}
__device__ __forceinline__ int dst_at(const u32* ei32, int t, int E, int fI) {
    return (int)(fI ? ei32[2 * (E + t)] : ei32[E + t]);
}

// ---------------------------------------------------------------------------
// Convert all small weights/biases -> fp32 in workspace, plus W1 split into
// bf16 hi/lo MFMA B-fragments:
//   w1b [kb*512 + lane*8 + j] = bf16(W1[kb*32 + (lane>>4)*8 + j][lane&15])
//   w1bl[...same...]          = bf16(W1[...] - fp32(w1b[...]))
// (bf16x3 split: x.w = xh.wh + xl.wh + xh.wl recovers fp32-level accuracy.)
// ---------------------------------------------------------------------------
__global__ __launch_bounds__(256) void prep_weights(
    const void* __restrict__ W1, const void* __restrict__ W2,
    const void* __restrict__ fcw, const void* __restrict__ cw1,
    const void* __restrict__ cw2, const void* __restrict__ b1,
    const void* __restrict__ b2, const void* __restrict__ fcb,
    const void* __restrict__ cb1, const void* __restrict__ cb2,
    const int* __restrict__ flags,
    float* __restrict__ w1f, float* __restrict__ w2f, float* __restrict__ fcwf,
    float* __restrict__ cw1f, float* __restrict__ cw2f, float* __restrict__ b1f,
    float* __restrict__ b2f, float* __restrict__ fcbf, float* __restrict__ cb1f,
    float* __restrict__ cb2f, u16* __restrict__ w1b, u16* __restrict__ w1bl)
{
    int fF = flags[0];
    int t = blockIdx.x * blockDim.x + threadIdx.x;
    if (t < 8192) { w1f[t] = ldw(W1, t, fF); return; }
    int u = t - 8192;
    if (u < 256)  { w2f[u]  = ldw(W2, u, fF);  return; }  u -= 256;
    if (u < 16)   { fcwf[u] = ldw(fcw, u, fF); return; }  u -= 16;
    if (u < 2048) { cw1f[u] = ldw(cw1, u, fF); return; }  u -= 2048;
    if (u < 16)   { cw2f[u] = ldw(cw2, u, fF); return; }  u -= 16;
    if (u < 16)   { b1f[u]  = ldw(b1, u, fF);  return; }  u -= 16;
    if (u < 16)   { b2f[u]  = ldw(b2, u, fF);  return; }  u -= 16;
    if (u < 1)    { fcbf[u] = ldw(fcb, u, fF); return; }  u -= 1;
    if (u < 16)   { cb1f[u] = ldw(cb1, u, fF); return; }  u -= 16;
    if (u < 1)    { cb2f[u] = ldw(cb2, u, fF); return; }  u -= 1;
    if (u < 8192) {
        int kb = u >> 9;           // K-block (16)
        int r  = (u >> 3) & 63;    // lane (64)
        int j  = u & 7;            // elem (8)
        float w = ldw(W1, (kb * 32 + (r >> 4) * 8 + j) * 16 + (r & 15), fF);
        u16 hi = f2bf(w);
        w1b[u]  = hi;
        w1bl[u] = f2bf(w - bf2f(hi));
        return;
    }
}

// ---------------------------------------------------------------------------
// Degree count (graph shared across batch -> computed once). deg pre-zeroed.
// ---------------------------------------------------------------------------
__global__ __launch_bounds__(256) void deg_k(const u32* __restrict__ ei32,
                                             const int* __restrict__ flags,
                                             int* __restrict__ deg, int E)
{
    int t = blockIdx.x * blockDim.x + threadIdx.x;
    if (t >= E) return;
    int d = dst_at(ei32, t, E, flags[1]);
    if ((unsigned)d < (unsigned)N_) atomicAdd(&deg[d], 1);
}

// ---------------------------------------------------------------------------
// Single-block exclusive scan over deg[5000] -> rowptr/cursor, plus dinv.
// ---------------------------------------------------------------------------
__global__ __launch_bounds__(1024) void scan_k(const int* __restrict__ deg,
                                               int* __restrict__ rowptr,
                                               int* __restrict__ cursor,
                                               float* __restrict__ dinv)
{
    __shared__ int ssum[1024];
    int t = threadIdx.x;
    int base = t * 5;
    int loc[5];
    int run = 0;
#pragma unroll
    for (int i = 0; i < 5; i++) {
        int idx = base + i;
        int v = (idx < N_) ? deg[idx] : 0;
        loc[i] = run;
        run += v;
    }
    ssum[t] = run;
    __syncthreads();
    for (int offs = 1; offs < 1024; offs <<= 1) {
        int v = (t >= offs) ? ssum[t - offs] : 0;
        __syncthreads();
        ssum[t] += v;
        __syncthreads();
    }
    int exclusive = ssum[t] - run;
#pragma unroll
    for (int i = 0; i < 5; i++) {
        int idx = base + i;
        if (idx < N_) {
            int rp = exclusive + loc[i];
            rowptr[idx] = rp;
            cursor[idx] = rp;
            dinv[idx] = 1.0f / sqrtf((float)deg[idx] + 1.0f);  // +1 self loop
        }
    }
    if (t == 1023) rowptr[N_] = ssum[1023];
}

// ---------------------------------------------------------------------------
// CSR fill: csr[rowptr[d] ...] = list of src nodes with an edge into d.
// ---------------------------------------------------------------------------
__global__ __launch_bounds__(256) void fill_k(const u32* __restrict__ ei32,
                                              const int* __restrict__ flags,
                                              int* __restrict__ cursor,
                                              int* __restrict__ csr, int E)
{
    int t = blockIdx.x * blockDim.x + threadIdx.x;
    if (t >= E) return;
    int fI = flags[1];
    int s = src_at(ei32, t, E, fI);
    int d = dst_at(ei32, t, E, fI);
    if ((unsigned)d >= (unsigned)N_) return;
    if ((unsigned)s >= (unsigned)N_) s = 0;    // guard (only if detection wrong)
    int pos = atomicAdd(&cursor[d], 1);
    if ((unsigned)pos < (unsigned)E) csr[pos] = s;
}

// ---------------------------------------------------------------------------
// GEMM1: H'[n][b][k] = dinv[n] * sum_f x[b,n,f] * W1[f,k]
// MFMA bf16x3-split version (r10 post-mortem: ALL VALU variants pin at
// ~72us on the weight-BROADCAST mechanism — divergent VMEM or SMEM-K$
// thrash. MFMA fragments hold weights DISTRIBUTED in VGPRs: no broadcast,
// no SMEM, no LDS, no barrier.)
//   fp32 input: per kb, load 8 fp32/lane (wave = 16 rows x 128B contiguous,
//   full 64B lines), split to bf16 hi/lo in regs, then 3 chained MFMAs:
//   acc += xh.wh + xl.wh + xh.wl  (drops xl.wl ~2^-18 rel -> fp32-accurate).
//   bf16 input: single-MFMA path (dtype insurance).
// A-frag: row=lane&15, k=(lane>>4)*8+j. B-frag: col=lane&15, same k.
// C/D (m89-verified): col=lane&15, row=(lane>>4)*4+reg.
// Output layout [n][16b][16k] so agg gathers are dense 512B segments.
// ---------------------------------------------------------------------------
__global__ __launch_bounds__(256) void gemm1_k(const void* __restrict__ xraw,
                                               const u16* __restrict__ w1b,
                                               const u16* __restrict__ w1bl,
                                               const float* __restrict__ dinv,
                                               const int* __restrict__ flags,
                                               u16* __restrict__ out)
{
    const int t    = threadIdx.x;
    const int lane = t & 63;
    const int wv   = t >> 6;            // 0..3
    const int row0 = blockIdx.x * 64;   // NT = 1250*64 exactly
    const int fF   = flags[0];

    f32x4 acc = {0.0f, 0.0f, 0.0f, 0.0f};

    if (fF) {
        // ---- bf16 input: single-MFMA path ----
        const u16* xr = (const u16*)xraw
                      + (size_t)(row0 + wv * 16 + (lane & 15)) * F_
                      + (lane >> 4) * 8;
#pragma unroll
        for (int kb = 0; kb < 16; kb++) {
            bf16x8 a = *(const bf16x8*)(xr + kb * 32);
            bf16x8 w = *(const bf16x8*)(w1b + kb * 512 + lane * 8);
            acc = __builtin_amdgcn_mfma_f32_16x16x32_bf16(a, w, acc, 0, 0, 0);
        }
    } else {
        // ---- fp32 input: bf16x3 split MFMA ----
        const float* xr = (const float*)xraw
                        + (size_t)(row0 + wv * 16 + (lane & 15)) * F_
                        + (lane >> 4) * 8;
#pragma unroll
        for (int kb = 0; kb < 16; kb++) {
            float4 a0 = *(const float4*)(xr + kb * 32);
            float4 a1 = *(const float4*)(xr + kb * 32 + 4);
            float av[8] = {a0.x, a0.y, a0.z, a0.w, a1.x, a1.y, a1.z, a1.w};
            union { bf16x8 v; u16 h[8]; } ahi, alo;
#pragma unroll
            for (int j = 0; j < 8; j++) {
                u16 hi = f2bf(av[j]);
                ahi.h[j] = hi;
                alo.h[j] = f2bf(av[j] - bf2f(hi));
            }
            union { bf16x8 v; uint4 u; } whi, wlo;
            whi.u = *(const uint4*)(w1b  + kb * 512 + lane * 8);
            wlo.u = *(const uint4*)(w1bl + kb * 512 + lane * 8);
            acc = __builtin_amdgcn_mfma_f32_16x16x32_bf16(ahi.v, whi.v, acc, 0, 0, 0);
            acc = __builtin_amdgcn_mfma_f32_16x16x32_bf16(alo.v, whi.v, acc, 0, 0, 0);
            acc = __builtin_amdgcn_mfma_f32_16x16x32_bf16(ahi.v, wlo.v, acc, 0, 0, 0);
        }
    }

#pragma unroll
    for (int i = 0; i < 4; i++) {
        int grow = row0 + wv * 16 + (lane >> 4) * 4 + i;
        int n  = grow % N_;
        int bb = grow / N_;
        out[(size_t)n * 256 + bb * 16 + (lane & 15)] = f2bf(acc[i] * dinv[n]);
    }
}

// ---------------------------------------------------------------------------
// Aggregation 1 + fused GEMM2. One block per NODE d, covering all 16 batches
// (tid = b*16 + k). H layout [n][b][k]: each edge gather is one dense 512B
// segment read by the whole block (fully coalesced); csr read once per node.
//   x1[b,k]    = relu(dinv[d]*(H'[d,b,k] + sum_{s->d} H'[s,b,k]) + b1[k])
//   H2'[d,b,k] = dinv[d] * sum_j x1[b,j] * W2[j,k]      (16-lane shfl)
// ---------------------------------------------------------------------------
__global__ __launch_bounds__(256) void agg1_k(const u16* __restrict__ h,
                                              const int* __restrict__ rowptr,
                                              const int* __restrict__ csr,
                                              const float* __restrict__ dinv,
                                              const float* __restrict__ b1f,
                                              const float* __restrict__ w2f,
                                              u16* __restrict__ out)
{
    int d   = blockIdx.x;          // 0..N_-1
    int tid = threadIdx.x;         // b*16 + k
    int k   = tid & 15;
    float acc = bf2f(h[(size_t)d * 256 + tid]);   // self loop
    int e0 = rowptr[d], e1 = rowptr[d + 1];
    for (int base = e0; base < e1; base += 8) {
        int idx[8];
#pragma unroll
        for (int j = 0; j < 8; j++) {
            int e = base + j;
            idx[j] = csr[e < e1 ? e : e0];
        }
        float v[8];
#pragma unroll
        for (int j = 0; j < 8; j++) v[j] = bf2f(h[(size_t)idx[j] * 256 + tid]);
#pragma unroll
        for (int j = 0; j < 8; j++) if (base + j < e1) acc += v[j];
    }
    float dv = dinv[d];
    float x1 = fmaxf(acc * dv + b1f[k], 0.0f);
    // fused 16x16 GEMM2 (X1 stays fp32)
    float h2 = 0.0f;
#pragma unroll
    for (int j = 0; j < 16; j++) {
        float xj = __shfl(x1, j, 16);
        h2 += xj * w2f[j * 16 + k];
    }
    out[(size_t)d * 256 + tid] = f2bf(h2 * dv);
}

// ---------------------------------------------------------------------------
// Aggregation 2 + fused node head. Same per-node block structure.
//   x2[b,k] = relu(dinv[d]*(H2'[d,b,k] + sum H2'[s,b,k]) + b2[k])
//   nl[b,d] = sum_k x2[b,k]*fc_w[k] + fc_b     (16-lane shfl reduction)
// ---------------------------------------------------------------------------
__global__ __launch_bounds__(256) void agg2_k(const u16* __restrict__ h,
                                              const int* __restrict__ rowptr,
                                              const int* __restrict__ csr,
                                              const float* __restrict__ dinv,
                                              const float* __restrict__ b2f,
                                              const float* __restrict__ fcwf,
                                              const float* __restrict__ fcbf,
                                              float* __restrict__ nl)
{
    int d   = blockIdx.x;
    int tid = threadIdx.x;
    int k   = tid & 15;
    int b   = tid >> 4;
    float acc = bf2f(h[(size_t)d * 256 + tid]);
    int e0 = rowptr[d], e1 = rowptr[d + 1];
    for (int base = e0; base < e1; base += 8) {
        int idx[8];
#pragma unroll
        for (int j = 0; j < 8; j++) {
            int e = base + j;
            idx[j] = csr[e < e1 ? e : e0];
        }
        float v[8];
#pragma unroll
        for (int j = 0; j < 8; j++) v[j] = bf2f(h[(size_t)idx[j] * 256 + tid]);
#pragma unroll
        for (int j = 0; j < 8; j++) if (base + j < e1) acc += v[j];
    }
    float x2 = fmaxf(acc * dinv[d] + b2f[k], 0.0f);
    float p = x2 * fcwf[k];
    p += __shfl_xor(p, 8, 16);
    p += __shfl_xor(p, 4, 16);
    p += __shfl_xor(p, 2, 16);
    p += __shfl_xor(p, 1, 16);
    if (k == 0) nl[b * N_ + d] = p + fcbf[0];
}

// ---------------------------------------------------------------------------
// Column MLP: cl[b,c] = (relu(cf[b,c,:] @ cw1 + cb1)) @ cw2 + cb2
// ---------------------------------------------------------------------------
__global__ __launch_bounds__(256) void col_k(const void* __restrict__ cfraw,
                                             const float* __restrict__ cw1f,
                                             const float* __restrict__ cb1f,
                                             const float* __restrict__ cw2f,
                                             const float* __restrict__ cb2f,
                                             const int* __restrict__ flags,
                                             float* __restrict__ cl)
{
    int t = blockIdx.x * blockDim.x + threadIdx.x;
    if (t >= B_ * C_) return;
    float acc[16];
#pragma unroll
    for (int k = 0; k < 16; k++) acc[k] = cb1f[k];
    if (flags[0]) {
        const u16* r = (const u16*)cfraw + (size_t)t * FC_;
        for (int f = 0; f < FC_; f += 8) {
            uint4 pk = *(const uint4*)(r + f);
            u32 q[4] = {pk.x, pk.y, pk.z, pk.w};
#pragma unroll
            for (int j = 0; j < 4; j++) {
                float v0 = bf2f((u16)(q[j] & 0xffffu));
                float v1 = bf2f((u16)(q[j] >> 16));
                const float* w0 = cw1f + (f + 2 * j) * 16;
#pragma unroll
                for (int k = 0; k < 16; k++) acc[k] += v0 * w0[k];
#pragma unroll
                for (int k = 0; k < 16; k++) acc[k] += v1 * w0[16 + k];
            }
        }
    } else {
        const float* r = (const float*)cfraw + (size_t)t * FC_;
        for (int f = 0; f < FC_; f += 4) {
            float4 a = *(const float4*)(r + f);
            float v[4] = {a.x, a.y, a.z, a.w};
#pragma unroll
            for (int j = 0; j < 4; j++) {
                const float* w0 = cw1f + (f + j) * 16;
#pragma unroll
                for (int k = 0; k < 16; k++) acc[k] += v[j] * w0[k];
            }
        }
    }
    float s = cb2f[0];
#pragma unroll
    for (int k = 0; k < 16; k++) s += fmaxf(acc[k], 0.0f) * cw2f[k];
    cl[t] = s;
}

// ---------------------------------------------------------------------------
// Join: out[b, n*C + c] = nl[b,n] + cl[b,c]; output dtype follows input dtype
// ---------------------------------------------------------------------------
__global__ __launch_bounds__(256) void join_k(const float* __restrict__ nl,
                                              const float* __restrict__ cl,
                                              const int* __restrict__ flags,
                                              void* __restrict__ outraw)
{
    int t = blockIdx.x * blockDim.x + threadIdx.x;
    if (t >= NT * C_ / 8) return;
    int g  = t >> 3;          // b*N + n
    int c0 = (t & 7) * 8;
    int b  = g / N_;
    float nv = nl[g];
    const float* c = cl + b * C_ + c0;
    float4 a0 = *(const float4*)c;
    float4 a1 = *(const float4*)(c + 4);
    float v[8] = {a0.x, a0.y, a0.z, a0.w, a1.x, a1.y, a1.z, a1.w};
#pragma unroll
    for (int i = 0; i < 8; i++) v[i] += nv;
    size_t idx = (size_t)g * C_ + c0;
    if (flags[0]) {
        union { uint4 u; u16 h[8]; } pkv;
#pragma unroll
        for (int i = 0; i < 8; i++) pkv.h[i] = f2bf(v[i]);
        *(uint4*)((u16*)outraw + idx) = pkv.u;
    } else {
        float* o = (float*)outraw + idx;
        *(float4*)o       = make_float4(v[0], v[1], v[2], v[3]);
        *(float4*)(o + 4) = make_float4(v[4], v[5], v[6], v[7]);
    }
}

// ---------------------------------------------------------------------------
extern "C" void kernel_launch(void* const* d_in, const int* in_sizes, int n_in,
                              void* d_out, int out_size, void* d_ws, size_t ws_size,
                              hipStream_t stream)
{
    const void* x    = d_in[0];              // node_features  [B,N,F]
    const void* cf   = d_in[1];              // col_features   [B,C,FC]
    const u32*  ei32 = (const u32*)d_in[2];  // edge_index     [2,E] int32 or int64
    const void* W1   = d_in[3];
    const void* b1   = d_in[4];
    const void* W2   = d_in[5];
    const void* b2   = d_in[6];
    const void* fcw  = d_in[7];
    const void* fcb  = d_in[8];
    const void* cw1  = d_in[9];
    const void* cb1  = d_in[10];
    const void* cw2  = d_in[11];
    const void* cb2  = d_in[12];

    const int E = in_sizes[2] / 2;

    // workspace layout (~6.3 MB)
    char* base = (char*)d_ws;
    size_t off = 0;
    auto alloc = [&](size_t bytes) -> void* {
        void* p = base + off;
        off = (off + bytes + 255) & ~(size_t)255;
        return p;
    };
    int*   flags  = (int*)alloc(2 * 4);
    float* w1f  = (float*)alloc(8192 * 4);
    u16*   w1b  = (u16*)alloc(8192 * 2);    // W1 bf16 hi, MFMA B-frag order
    u16*   w1bl = (u16*)alloc(8192 * 2);    // W1 bf16 lo residual
    float* w2f  = (float*)alloc(256 * 4);
    float* fcwf = (float*)alloc(16 * 4);
    float* cw1f = (float*)alloc(2048 * 4);
    float* cw2f = (float*)alloc(16 * 4);
    float* b1f  = (float*)alloc(16 * 4);
    float* b2f  = (float*)alloc(16 * 4);
    float* fcbf = (float*)alloc(4);
    float* cb1f = (float*)alloc(16 * 4);
    float* cb2f = (float*)alloc(4);
    int*   deg    = (int*)alloc((size_t)N_ * 4);
    int*   rowptr = (int*)alloc((size_t)(N_ + 1) * 4);
    int*   cursor = (int*)alloc((size_t)N_ * 4);
    float* dinv   = (float*)alloc((size_t)N_ * 4);
    int*   csr    = (int*)alloc((size_t)E * 4);
    u16*   bufA = (u16*)alloc((size_t)NT * 16 * 2);   // H'  (bf16, [n][b][k])
    u16*   bufB = (u16*)alloc((size_t)NT * 16 * 2);   // H2' (bf16, [n][b][k])
    float* nl   = (float*)alloc((size_t)NT * 4);
    float* cl   = (float*)alloc((size_t)B_ * C_ * 4);

    det_k<<<1, 256, 0, stream>>>((const u32*)x, ei32, flags);
    hipMemsetAsync(deg, 0, (size_t)N_ * 4, stream);
    prep_weights<<<(10578 + 8192 + 255) / 256, 256, 0, stream>>>(
        W1, W2, fcw, cw1, cw2, b1, b2, fcb, cb1, cb2, flags,
        w1f, w2f, fcwf, cw1f, cw2f, b1f, b2f, fcbf, cb1f, cb2f, w1b, w1bl);
    deg_k<<<(E + 255) / 256, 256, 0, stream>>>(ei32, flags, deg, E);
    scan_k<<<1, 1024, 0, stream>>>(deg, rowptr, cursor, dinv);
    fill_k<<<(E + 255) / 256, 256, 0, stream>>>(ei32, flags, cursor, csr, E);

    gemm1_k<<<NT / 64, 256, 0, stream>>>(x, w1b, w1bl, dinv, flags, bufA);
    agg1_k<<<N_, 256, 0, stream>>>(bufA, rowptr, csr, dinv, b1f, w2f, bufB);
    agg2_k<<<N_, 256, 0, stream>>>(bufB, rowptr, csr, dinv, b2f, fcwf, fcbf, nl);
    col_k<<<(B_ * C_ + 255) / 256, 256, 0, stream>>>(cf, cw1f, cb1f, cw2f, cb2f, flags, cl);
    join_k<<<(NT * C_ / 8 + 255) / 256, 256, 0, stream>>>(nl, cl, flags, d_out);
}

// Round 12
// 358.342 us; speedup vs baseline: 1.0227x; 1.0035x over previous
//
#include <hip/hip_runtime.h>
#include <hip/hip_bf16.h>

typedef unsigned short u16;
typedef unsigned int   u32;
typedef __attribute__((ext_vector_type(8))) short bf16x8;   // 8 bf16 = 4 VGPR
typedef __attribute__((ext_vector_type(4))) float f32x4;    // MFMA accum

#define B_  16
#define N_  5000
#define F_  512
#define C_  64
#define FC_ 128
#define NT  (B_ * N_)   // 80000 total nodes

__device__ __forceinline__ float bf2f(u16 h) {
    return __uint_as_float(((u32)h) << 16);
}
__device__ __forceinline__ u16 f2bf(float f) {
    union { __hip_bfloat16 h; u16 s; } c; c.h = __float2bfloat16(f); return c.s;
}
// dtype-flexible scalar weight load (fF: 1 = bf16 data, 0 = fp32 data)
__device__ __forceinline__ float ldw(const void* p, int i, int fF) {
    return fF ? bf2f(((const u16*)p)[i]) : ((const float*)p)[i];
}

// ---------------------------------------------------------------------------
// Detector: flags[0] = 1 if float tensors are bf16 (else fp32)
//           flags[1] = 1 if edge_index is int64 (else int32)
// NOTE (r7): harness inputs are fp32 -> flags[0]=0 in practice.
// ---------------------------------------------------------------------------
__global__ __launch_bounds__(256) void det_k(const u32* __restrict__ x32,
                                             const u32* __restrict__ ei32,
                                             int* __restrict__ flags)
{
    __shared__ int cnt;
    __shared__ int orv;
    if (threadIdx.x == 0) { cnt = 0; orv = 0; }
    __syncthreads();
    u32 w = x32[threadIdx.x];
    int e = (int)((w >> 7) & 0xffu);          // exponent field of low-u16-as-bf16
    if (e >= 112 && e <= 136) atomicAdd(&cnt, 1);
    if (threadIdx.x < 32) {
        if (ei32[2 * threadIdx.x + 1] != 0u) atomicOr(&orv, 1);
    }
    __syncthreads();
    if (threadIdx.x == 0) {
        flags[0] = (cnt >= 128) ? 1 : 0;
        flags[1] = (orv == 0) ? 1 : 0;
    }
}

// edge index accessors (ei32 = edge_index buffer viewed as u32)
__device__ __forceinline__ int src_at(const u32* ei32, int t, int E, int fI) {
    return (int)(fI ? ei32[2 * t] : ei32[t]);
}
__device__ __forceinline__ int dst_at(const u32* ei32, int t, int E, int fI) {
    return (int)(fI ? ei32[2 * (E + t)] : ei32[E + t]);
}

// ---------------------------------------------------------------------------
// Convert all small weights/biases -> fp32 in workspace, plus W1 split into
// bf16 hi/lo MFMA B-fragments:
//   w1b [kb*512 + lane*8 + j] = bf16(W1[kb*32 + (lane>>4)*8 + j][lane&15])
//   w1bl[...same...]          = bf16(W1[...] - fp32(w1b[...]))
// (bf16x3 split: x.w = xh.wh + xl.wh + xh.wl recovers fp32-level accuracy.)
// ---------------------------------------------------------------------------
__global__ __launch_bounds__(256) void prep_weights(
    const void* __restrict__ W1, const void* __restrict__ W2,
    const void* __restrict__ fcw, const void* __restrict__ cw1,
    const void* __restrict__ cw2, const void* __restrict__ b1,
    const void* __restrict__ b2, const void* __restrict__ fcb,
    const void* __restrict__ cb1, const void* __restrict__ cb2,
    const int* __restrict__ flags,
    float* __restrict__ w1f, float* __restrict__ w2f, float* __restrict__ fcwf,
    float* __restrict__ cw1f, float* __restrict__ cw2f, float* __restrict__ b1f,
    float* __restrict__ b2f, float* __restrict__ fcbf, float* __restrict__ cb1f,
    float* __restrict__ cb2f, u16* __restrict__ w1b, u16* __restrict__ w1bl)
{
    int fF = flags[0];
    int t = blockIdx.x * blockDim.x + threadIdx.x;
    if (t < 8192) { w1f[t] = ldw(W1, t, fF); return; }
    int u = t - 8192;
    if (u < 256)  { w2f[u]  = ldw(W2, u, fF);  return; }  u -= 256;
    if (u < 16)   { fcwf[u] = ldw(fcw, u, fF); return; }  u -= 16;
    if (u < 2048) { cw1f[u] = ldw(cw1, u, fF); return; }  u -= 2048;
    if (u < 16)   { cw2f[u] = ldw(cw2, u, fF); return; }  u -= 16;
    if (u < 16)   { b1f[u]  = ldw(b1, u, fF);  return; }  u -= 16;
    if (u < 16)   { b2f[u]  = ldw(b2, u, fF);  return; }  u -= 16;
    if (u < 1)    { fcbf[u] = ldw(fcb, u, fF); return; }  u -= 1;
    if (u < 16)   { cb1f[u] = ldw(cb1, u, fF); return; }  u -= 16;
    if (u < 1)    { cb2f[u] = ldw(cb2, u, fF); return; }  u -= 1;
    if (u < 8192) {
        int kb = u >> 9;           // K-block (16)
        int r  = (u >> 3) & 63;    // lane (64)
        int j  = u & 7;            // elem (8)
        float w = ldw(W1, (kb * 32 + (r >> 4) * 8 + j) * 16 + (r & 15), fF);
        u16 hi = f2bf(w);
        w1b[u]  = hi;
        w1bl[u] = f2bf(w - bf2f(hi));
        return;
    }
}

// ---------------------------------------------------------------------------
// Degree count (graph shared across batch -> computed once). deg pre-zeroed.
// ---------------------------------------------------------------------------
__global__ __launch_bounds__(256) void deg_k(const u32* __restrict__ ei32,
                                             const int* __restrict__ flags,
                                             int* __restrict__ deg, int E)
{
    int t = blockIdx.x * blockDim.x + threadIdx.x;
    if (t >= E) return;
    int d = dst_at(ei32, t, E, flags[1]);
    if ((unsigned)d < (unsigned)N_) atomicAdd(&deg[d], 1);
}

// ---------------------------------------------------------------------------
// Single-block exclusive scan over deg[5000] -> rowptr/cursor, plus dinv.
// ---------------------------------------------------------------------------
__global__ __launch_bounds__(1024) void scan_k(const int* __restrict__ deg,
                                               int* __restrict__ rowptr,
                                               int* __restrict__ cursor,
                                               float* __restrict__ dinv)
{
    __shared__ int ssum[1024];
    int t = threadIdx.x;
    int base = t * 5;
    int loc[5];
    int run = 0;
#pragma unroll
    for (int i = 0; i < 5; i++) {
        int idx = base + i;
        int v = (idx < N_) ? deg[idx] : 0;
        loc[i] = run;
        run += v;
    }
    ssum[t] = run;
    __syncthreads();
    for (int offs = 1; offs < 1024; offs <<= 1) {
        int v = (t >= offs) ? ssum[t - offs] : 0;
        __syncthreads();
        ssum[t] += v;
        __syncthreads();
    }
    int exclusive = ssum[t] - run;
#pragma unroll
    for (int i = 0; i < 5; i++) {
        int idx = base + i;
        if (idx < N_) {
            int rp = exclusive + loc[i];
            rowptr[idx] = rp;
            cursor[idx] = rp;
            dinv[idx] = 1.0f / sqrtf((float)deg[idx] + 1.0f);  // +1 self loop
        }
    }
    if (t == 1023) rowptr[N_] = ssum[1023];
}

// ---------------------------------------------------------------------------
// CSR fill: csr[rowptr[d] ...] = list of src nodes with an edge into d.
// ---------------------------------------------------------------------------
__global__ __launch_bounds__(256) void fill_k(const u32* __restrict__ ei32,
                                              const int* __restrict__ flags,
                                              int* __restrict__ cursor,
                                              int* __restrict__ csr, int E)
{
    int t = blockIdx.x * blockDim.x + threadIdx.x;
    if (t >= E) return;
    int fI = flags[1];
    int s = src_at(ei32, t, E, fI);
    int d = dst_at(ei32, t, E, fI);
    if ((unsigned)d >= (unsigned)N_) return;
    if ((unsigned)s >= (unsigned)N_) s = 0;    // guard (only if detection wrong)
    int pos = atomicAdd(&cursor[d], 1);
    if ((unsigned)pos < (unsigned)E) csr[pos] = s;
}

// ---------------------------------------------------------------------------
// GEMM1: H'[n][b][k] = dinv[n] * sum_f x[b,n,f] * W1[f,k]
// MFMA bf16x3 with GROUPED PREFETCH (r11 post-mortem: per-kb serialized
// load->cvt->wload->MFMA left ~2 loads in flight; latency-bound at 66us).
// Groups of 4 kb: issue all 16 group loads (8 x-float4 + 8 w-uint4) before
// any compute of the group; launch_bounds(256,4) caps VGPR at 128 so 4
// waves/SIMD stay resident. In-flight bytes/CU >> BW-latency product.
// Arithmetic per kb identical to r11 (same order) -> bit-identical output.
// A-frag: row=lane&15, k=(lane>>4)*8+j. C/D: col=lane&15, row=(lane>>4)*4+reg.
// Output layout [n][16b][16k] so agg gathers are dense 512B segments.
// ---------------------------------------------------------------------------
__global__ __launch_bounds__(256, 4) void gemm1_k(const void* __restrict__ xraw,
                                                  const u16* __restrict__ w1b,
                                                  const u16* __restrict__ w1bl,
                                                  const float* __restrict__ dinv,
                                                  const int* __restrict__ flags,
                                                  u16* __restrict__ out)
{
    const int t    = threadIdx.x;
    const int lane = t & 63;
    const int wv   = t >> 6;            // 0..3
    const int row0 = blockIdx.x * 64;   // NT = 1250*64 exactly
    const int fF   = flags[0];

    f32x4 acc = {0.0f, 0.0f, 0.0f, 0.0f};

    if (fF) {
        // ---- bf16 input: single-MFMA path (grouped loads) ----
        const u16* xr = (const u16*)xraw
                      + (size_t)(row0 + wv * 16 + (lane & 15)) * F_
                      + (lane >> 4) * 8;
#pragma unroll
        for (int g = 0; g < 4; g++) {
            bf16x8 a[4], w[4];
#pragma unroll
            for (int i = 0; i < 4; i++) {
                int kb = g * 4 + i;
                a[i] = *(const bf16x8*)(xr + kb * 32);
                w[i] = *(const bf16x8*)(w1b + kb * 512 + lane * 8);
            }
#pragma unroll
            for (int i = 0; i < 4; i++)
                acc = __builtin_amdgcn_mfma_f32_16x16x32_bf16(a[i], w[i], acc, 0, 0, 0);
        }
    } else {
        // ---- fp32 input: bf16x3 split MFMA, grouped prefetch ----
        const float* xr = (const float*)xraw
                        + (size_t)(row0 + wv * 16 + (lane & 15)) * F_
                        + (lane >> 4) * 8;
#pragma unroll
        for (int g = 0; g < 4; g++) {
            float4 xa[4][2];
            uint4  wh[4], wl[4];
            // issue ALL 16 loads of this group before any compute
#pragma unroll
            for (int i = 0; i < 4; i++) {
                int kb = g * 4 + i;
                xa[i][0] = *(const float4*)(xr + kb * 32);
                xa[i][1] = *(const float4*)(xr + kb * 32 + 4);
                wh[i] = *(const uint4*)(w1b  + kb * 512 + lane * 8);
                wl[i] = *(const uint4*)(w1bl + kb * 512 + lane * 8);
            }
            // compute the group (same per-kb order as r11 -> bit-identical)
#pragma unroll
            for (int i = 0; i < 4; i++) {
                float av[8] = {xa[i][0].x, xa[i][0].y, xa[i][0].z, xa[i][0].w,
                               xa[i][1].x, xa[i][1].y, xa[i][1].z, xa[i][1].w};
                union { bf16x8 v; u16 h[8]; } ahi, alo;
#pragma unroll
                for (int j = 0; j < 8; j++) {
                    u16 hi = f2bf(av[j]);
                    ahi.h[j] = hi;
                    alo.h[j] = f2bf(av[j] - bf2f(hi));
                }
                union { bf16x8 v; uint4 u; } whi, wlo;
                whi.u = wh[i];
                wlo.u = wl[i];
                acc = __builtin_amdgcn_mfma_f32_16x16x32_bf16(ahi.v, whi.v, acc, 0, 0, 0);
                acc = __builtin_amdgcn_mfma_f32_16x16x32_bf16(alo.v, whi.v, acc, 0, 0, 0);
                acc = __builtin_amdgcn_mfma_f32_16x16x32_bf16(ahi.v, wlo.v, acc, 0, 0, 0);
            }
        }
    }

#pragma unroll
    for (int i = 0; i < 4; i++) {
        int grow = row0 + wv * 16 + (lane >> 4) * 4 + i;
        int n  = grow % N_;
        int bb = grow / N_;
        out[(size_t)n * 256 + bb * 16 + (lane & 15)] = f2bf(acc[i] * dinv[n]);
    }
}

// ---------------------------------------------------------------------------
// Aggregation 1 + fused GEMM2. One block per NODE d, covering all 16 batches
// (tid = b*16 + k). H layout [n][b][k]: each edge gather is one dense 512B
// segment read by the whole block (fully coalesced); csr read once per node.
//   x1[b,k]    = relu(dinv[d]*(H'[d,b,k] + sum_{s->d} H'[s,b,k]) + b1[k])
//   H2'[d,b,k] = dinv[d] * sum_j x1[b,j] * W2[j,k]      (16-lane shfl)
// ---------------------------------------------------------------------------
__global__ __launch_bounds__(256) void agg1_k(const u16* __restrict__ h,
                                              const int* __restrict__ rowptr,
                                              const int* __restrict__ csr,
                                              const float* __restrict__ dinv,
                                              const float* __restrict__ b1f,
                                              const float* __restrict__ w2f,
                                              u16* __restrict__ out)
{
    int d   = blockIdx.x;          // 0..N_-1
    int tid = threadIdx.x;         // b*16 + k
    int k   = tid & 15;
    float acc = bf2f(h[(size_t)d * 256 + tid]);   // self loop
    int e0 = rowptr[d], e1 = rowptr[d + 1];
    for (int base = e0; base < e1; base += 8) {
        int idx[8];
#pragma unroll
        for (int j = 0; j < 8; j++) {
            int e = base + j;
            idx[j] = csr[e < e1 ? e : e0];
        }
        float v[8];
#pragma unroll
        for (int j = 0; j < 8; j++) v[j] = bf2f(h[(size_t)idx[j] * 256 + tid]);
#pragma unroll
        for (int j = 0; j < 8; j++) if (base + j < e1) acc += v[j];
    }
    float dv = dinv[d];
    float x1 = fmaxf(acc * dv + b1f[k], 0.0f);
    // fused 16x16 GEMM2 (X1 stays fp32)
    float h2 = 0.0f;
#pragma unroll
    for (int j = 0; j < 16; j++) {
        float xj = __shfl(x1, j, 16);
        h2 += xj * w2f[j * 16 + k];
    }
    out[(size_t)d * 256 + tid] = f2bf(h2 * dv);
}

// ---------------------------------------------------------------------------
// Aggregation 2 + fused node head. Same per-node block structure.
//   x2[b,k] = relu(dinv[d]*(H2'[d,b,k] + sum H2'[s,b,k]) + b2[k])
//   nl[b,d] = sum_k x2[b,k]*fc_w[k] + fc_b     (16-lane shfl reduction)
// ---------------------------------------------------------------------------
__global__ __launch_bounds__(256) void agg2_k(const u16* __restrict__ h,
                                              const int* __restrict__ rowptr,
                                              const int* __restrict__ csr,
                                              const float* __restrict__ dinv,
                                              const float* __restrict__ b2f,
                                              const float* __restrict__ fcwf,
                                              const float* __restrict__ fcbf,
                                              float* __restrict__ nl)
{
    int d   = blockIdx.x;
    int tid = threadIdx.x;
    int k   = tid & 15;
    int b   = tid >> 4;
    float acc = bf2f(h[(size_t)d * 256 + tid]);
    int e0 = rowptr[d], e1 = rowptr[d + 1];
    for (int base = e0; base < e1; base += 8) {
        int idx[8];
#pragma unroll
        for (int j = 0; j < 8; j++) {
            int e = base + j;
            idx[j] = csr[e < e1 ? e : e0];
        }
        float v[8];
#pragma unroll
        for (int j = 0; j < 8; j++) v[j] = bf2f(h[(size_t)idx[j] * 256 + tid]);
#pragma unroll
        for (int j = 0; j < 8; j++) if (base + j < e1) acc += v[j];
    }
    float x2 = fmaxf(acc * dinv[d] + b2f[k], 0.0f);
    float p = x2 * fcwf[k];
    p += __shfl_xor(p, 8, 16);
    p += __shfl_xor(p, 4, 16);
    p += __shfl_xor(p, 2, 16);
    p += __shfl_xor(p, 1, 16);
    if (k == 0) nl[b * N_ + d] = p + fcbf[0];
}

// ---------------------------------------------------------------------------
// Column MLP: cl[b,c] = (relu(cf[b,c,:] @ cw1 + cb1)) @ cw2 + cb2
// ---------------------------------------------------------------------------
__global__ __launch_bounds__(256) void col_k(const void* __restrict__ cfraw,
                                             const float* __restrict__ cw1f,
                                             const float* __restrict__ cb1f,
                                             const float* __restrict__ cw2f,
                                             const float* __restrict__ cb2f,
                                             const int* __restrict__ flags,
                                             float* __restrict__ cl)
{
    int t = blockIdx.x * blockDim.x + threadIdx.x;
    if (t >= B_ * C_) return;
    float acc[16];
#pragma unroll
    for (int k = 0; k < 16; k++) acc[k] = cb1f[k];
    if (flags[0]) {
        const u16* r = (const u16*)cfraw + (size_t)t * FC_;
        for (int f = 0; f < FC_; f += 8) {
            uint4 pk = *(const uint4*)(r + f);
            u32 q[4] = {pk.x, pk.y, pk.z, pk.w};
#pragma unroll
            for (int j = 0; j < 4; j++) {
                float v0 = bf2f((u16)(q[j] & 0xffffu));
                float v1 = bf2f((u16)(q[j] >> 16));
                const float* w0 = cw1f + (f + 2 * j) * 16;
#pragma unroll
                for (int k = 0; k < 16; k++) acc[k] += v0 * w0[k];
#pragma unroll
                for (int k = 0; k < 16; k++) acc[k] += v1 * w0[16 + k];
            }
        }
    } else {
        const float* r = (const float*)cfraw + (size_t)t * FC_;
        for (int f = 0; f < FC_; f += 4) {
            float4 a = *(const float4*)(r + f);
            float v[4] = {a.x, a.y, a.z, a.w};
#pragma unroll
            for (int j = 0; j < 4; j++) {
                const float* w0 = cw1f + (f + j) * 16;
#pragma unroll
                for (int k = 0; k < 16; k++) acc[k] += v[j] * w0[k];
            }
        }
    }
    float s = cb2f[0];
#pragma unroll
    for (int k = 0; k < 16; k++) s += fmaxf(acc[k], 0.0f) * cw2f[k];
    cl[t] = s;
}

// ---------------------------------------------------------------------------
// Join: out[b, n*C + c] = nl[b,n] + cl[b,c]; output dtype follows input dtype
// ---------------------------------------------------------------------------
__global__ __launch_bounds__(256) void join_k(const float* __restrict__ nl,
                                              const float* __restrict__ cl,
                                              const int* __restrict__ flags,
                                              void* __restrict__ outraw)
{
    int t = blockIdx.x * blockDim.x + threadIdx.x;
    if (t >= NT * C_ / 8) return;
    int g  = t >> 3;          // b*N + n
    int c0 = (t & 7) * 8;
    int b  = g / N_;
    float nv = nl[g];
    const float* c = cl + b * C_ + c0;
    float4 a0 = *(const float4*)c;
    float4 a1 = *(const float4*)(c + 4);
    float v[8] = {a0.x, a0.y, a0.z, a0.w, a1.x, a1.y, a1.z, a1.w};
#pragma unroll
    for (int i = 0; i < 8; i++) v[i] += nv;
    size_t idx = (size_t)g * C_ + c0;
    if (flags[0]) {
        union { uint4 u; u16 h[8]; } pkv;
#pragma unroll
        for (int i = 0; i < 8; i++) pkv.h[i] = f2bf(v[i]);
        *(uint4*)((u16*)outraw + idx) = pkv.u;
    } else {
        float* o = (float*)outraw + idx;
        *(float4*)o       = make_float4(v[0], v[1], v[2], v[3]);
        *(float4*)(o + 4) = make_float4(v[4], v[5], v[6], v[7]);
    }
}

// ---------------------------------------------------------------------------
extern "C" void kernel_launch(void* const* d_in, const int* in_sizes, int n_in,
                              void* d_out, int out_size, void* d_ws, size_t ws_size,
                              hipStream_t stream)
{
    const void* x    = d_in[0];              // node_features  [B,N,F]
    const void* cf   = d_in[1];              // col_features   [B,C,FC]
    const u32*  ei32 = (const u32*)d_in[2];  // edge_index     [2,E] int32 or int64
    const void* W1   = d_in[3];
    const void* b1   = d_in[4];
    const void* W2   = d_in[5];
    const void* b2   = d_in[6];
    const void* fcw  = d_in[7];
    const void* fcb  = d_in[8];
    const void* cw1  = d_in[9];
    const void* cb1  = d_in[10];
    const void* cw2  = d_in[11];
    const void* cb2  = d_in[12];

    const int E = in_sizes[2] / 2;

    // workspace layout (~6.3 MB)
    char* base = (char*)d_ws;
    size_t off = 0;
    auto alloc = [&](size_t bytes) -> void* {
        void* p = base + off;
        off = (off + bytes + 255) & ~(size_t)255;
        return p;
    };
    int*   flags  = (int*)alloc(2 * 4);
    float* w1f  = (float*)alloc(8192 * 4);
    u16*   w1b  = (u16*)alloc(8192 * 2);    // W1 bf16 hi, MFMA B-frag order
    u16*   w1bl = (u16*)alloc(8192 * 2);    // W1 bf16 lo residual
    float* w2f  = (float*)alloc(256 * 4);
    float* fcwf = (float*)alloc(16 * 4);
    float* cw1f = (float*)alloc(2048 * 4);
    float* cw2f = (float*)alloc(16 * 4);
    float* b1f  = (float*)alloc(16 * 4);
    float* b2f  = (float*)alloc(16 * 4);
    float* fcbf = (float*)alloc(4);
    float* cb1f = (float*)alloc(16 * 4);
    float* cb2f = (float*)alloc(4);
    int*   deg    = (int*)alloc((size_t)N_ * 4);
    int*   rowptr = (int*)alloc((size_t)(N_ + 1) * 4);
    int*   cursor = (int*)alloc((size_t)N_ * 4);
    float* dinv   = (float*)alloc((size_t)N_ * 4);
    int*   csr    = (int*)alloc((size_t)E * 4);
    u16*   bufA = (u16*)alloc((size_t)NT * 16 * 2);   // H'  (bf16, [n][b][k])
    u16*   bufB = (u16*)alloc((size_t)NT * 16 * 2);   // H2' (bf16, [n][b][k])
    float* nl   = (float*)alloc((size_t)NT * 4);
    float* cl   = (float*)alloc((size_t)B_ * C_ * 4);

    det_k<<<1, 256, 0, stream>>>((const u32*)x, ei32, flags);
    hipMemsetAsync(deg, 0, (size_t)N_ * 4, stream);
    prep_weights<<<(10578 + 8192 + 255) / 256, 256, 0, stream>>>(
        W1, W2, fcw, cw1, cw2, b1, b2, fcb, cb1, cb2, flags,
        w1f, w2f, fcwf, cw1f, cw2f, b1f, b2f, fcbf, cb1f, cb2f, w1b, w1bl);
    deg_k<<<(E + 255) / 256, 256, 0, stream>>>(ei32, flags, deg, E);
    scan_k<<<1, 1024, 0, stream>>>(deg, rowptr, cursor, dinv);
    fill_k<<<(E + 255) / 256, 256, 0, stream>>>(ei32, flags, cursor, csr, E);

    gemm1_k<<<NT / 64, 256, 0, stream>>>(x, w1b, w1bl, dinv, flags, bufA);
    agg1_k<<<N_, 256, 0, stream>>>(bufA, rowptr, csr, dinv, b1f, w2f, bufB);
    agg2_k<<<N_, 256, 0, stream>>>(bufB, rowptr, csr, dinv, b2f, fcwf, fcbf, nl);
    col_k<<<(B_ * C_ + 255) / 256, 256, 0, stream>>>(cf, cw1f, cb1f, cw2f, cb2f, flags, cl);
    join_k<<<(NT * C_ / 8 + 255) / 256, 256, 0, stream>>>(nl, cl, flags, d_out);
}